// Round 2
// baseline (6763.682 us; speedup 1.0000x reference)
//
#include <hip/hip_runtime.h>

#define N_NODES 100000
#define N_EDGES 600000
#define K_DIM   128
#define NPART   ((N_NODES + 255) / 256)   // 391 scan blocks

// ---------------------------------------------------------------- CSR build

__global__ void deg_kernel(const int* __restrict__ dst, int* __restrict__ deg) {
  int e = blockIdx.x * blockDim.x + threadIdx.x;
  if (e < N_EDGES) atomicAdd(&deg[dst[e]], 1);
}

__global__ void scan1_kernel(const int* __restrict__ deg, int* __restrict__ excl,
                             int* __restrict__ partials) {
  __shared__ int s[256];
  int t = threadIdx.x, i = blockIdx.x * 256 + t;
  int v = (i < N_NODES) ? deg[i] : 0;
  s[t] = v;
  __syncthreads();
  for (int off = 1; off < 256; off <<= 1) {
    int x = (t >= off) ? s[t - off] : 0;
    __syncthreads();
    s[t] += x;
    __syncthreads();
  }
  if (i < N_NODES) excl[i] = s[t] - v;
  if (t == 255) partials[blockIdx.x] = s[t];
}

__global__ void scan2_kernel(int* __restrict__ partials) {
  __shared__ int s[512];
  int t = threadIdx.x;
  int v = (t < NPART) ? partials[t] : 0;
  s[t] = v;
  __syncthreads();
  for (int off = 1; off < 512; off <<= 1) {
    int x = (t >= off) ? s[t - off] : 0;
    __syncthreads();
    s[t] += x;
    __syncthreads();
  }
  if (t < NPART) partials[t] = s[t] - v;   // exclusive block offsets
}

__global__ void scan3_kernel(const int* __restrict__ excl, const int* __restrict__ partials,
                             const int* __restrict__ deg, int* __restrict__ row_ptr,
                             int* __restrict__ cursor, float* __restrict__ inv_deg) {
  int i = blockIdx.x * blockDim.x + threadIdx.x;
  if (i < N_NODES) {
    int rp = excl[i] + partials[i >> 8];
    row_ptr[i] = rp;
    cursor[i] = rp;
    inv_deg[i] = 1.0f / (float)(deg[i] > 1 ? deg[i] : 1);
  } else if (i == N_NODES) {
    row_ptr[N_NODES] = N_EDGES;
  }
}

__global__ void fill_kernel(const int* __restrict__ src, const int* __restrict__ dst,
                            int* __restrict__ cursor, int* __restrict__ ssrc) {
  int e = blockIdx.x * blockDim.x + threadIdx.x;
  if (e < N_EDGES) {
    int p = atomicAdd(&cursor[dst[e]], 1);
    ssrc[p] = src[e];
  }
}

// ---------------------------------------------------------------- aggregate
// AGG[v] = inv_deg[v] * sum_{u->v} H[u].  8 lanes per row, 32 rows per block,
// zero LDS, 2-edge unroll for ILP. Latency-bound: occupancy is the lever.

__global__ __launch_bounds__(256, 6) void agg_kernel(
    const float* __restrict__ H, const int* __restrict__ row_ptr,
    const int* __restrict__ ssrc, const float* __restrict__ inv_deg,
    float* __restrict__ AGG) {
  const int tid = threadIdx.x;
  const int cg  = tid & 7;
  const int r   = tid >> 3;
  const int v   = blockIdx.x * 32 + r;
  if (v >= N_NODES) return;

  float a[16];
  #pragma unroll
  for (int i = 0; i < 16; ++i) a[i] = 0.f;

  const int beg = row_ptr[v], end = row_ptr[v + 1];
  int e = beg;
  for (; e + 2 <= end; e += 2) {
    const float* __restrict__ h0 = H + (size_t)ssrc[e] * K_DIM + cg * 4;
    const float* __restrict__ h1 = H + (size_t)ssrc[e + 1] * K_DIM + cg * 4;
    float4 t0[4], t1[4];
    #pragma unroll
    for (int i = 0; i < 4; ++i) t0[i] = *(const float4*)(h0 + i * 32);
    #pragma unroll
    for (int i = 0; i < 4; ++i) t1[i] = *(const float4*)(h1 + i * 32);
    #pragma unroll
    for (int i = 0; i < 4; ++i) {
      a[4 * i + 0] += t0[i].x + t1[i].x;
      a[4 * i + 1] += t0[i].y + t1[i].y;
      a[4 * i + 2] += t0[i].z + t1[i].z;
      a[4 * i + 3] += t0[i].w + t1[i].w;
    }
  }
  if (e < end) {
    const float* __restrict__ h0 = H + (size_t)ssrc[e] * K_DIM + cg * 4;
    #pragma unroll
    for (int i = 0; i < 4; ++i) {
      const float4 t = *(const float4*)(h0 + i * 32);
      a[4 * i + 0] += t.x; a[4 * i + 1] += t.y;
      a[4 * i + 2] += t.z; a[4 * i + 3] += t.w;
    }
  }
  const float sc = inv_deg[v];
  #pragma unroll
  for (int i = 0; i < 4; ++i)
    *(float4*)&AGG[(size_t)v * K_DIM + cg * 4 + i * 32] =
        make_float4(a[4 * i] * sc, a[4 * i + 1] * sc, a[4 * i + 2] * sc, a[4 * i + 3] * sc);
}

// ---------------------------------------------------------------- GEMM
// out = act(A1@W1 [+ A2@W2] + b).  128 rows x DOUT per block, 256 threads,
// thread = 4 rows x DOUT/8 cols. Weights staged in k-chunks of 32 through a
// double-buffered LDS (2 x 32*DOUT floats), register-prefetched: only
// 16/8 KB LDS per buffer -> 3 blocks/CU instead of 1.
// Alias note: each output row is read (A-side) and written by exactly the
// same 8-lane group of one wave, reads precede the store in program order,
// so `out` may alias A1 or A2 safely (OOB threads read clamped row N-1 but
// their stores are guarded, racy garbage is discarded).

template <int DOUT, bool TWO, bool RELU>
__global__ __launch_bounds__(256, 3) void gemm_kernel(
    const float* __restrict__ A1, const float* __restrict__ A2,
    const float* __restrict__ W1, const float* __restrict__ W2,
    const float* __restrict__ bias, float* __restrict__ out) {
  constexpr int CPT  = DOUT / 8;            // cols per thread: 16 or 8
  constexpr int NI   = CPT / 4;             // float4 groups: 4 or 2
  constexpr int CF   = 32 * DOUT;           // floats per k-chunk: 4096 or 2048
  constexpr int NSTG = CF / 1024;           // float4 stages per thread: 4 or 2
  constexpr int NCHUNK = TWO ? 8 : 4;

  __shared__ float sW[2][CF];

  const int tid = threadIdx.x;
  const int cg  = tid & 7;
  const int rg  = tid >> 3;
  const int row0 = blockIdx.x * 128 + rg * 4;

  int rowc[4];
  #pragma unroll
  for (int r = 0; r < 4; ++r) {
    int v = row0 + r;
    rowc[r] = v < N_NODES ? v : N_NODES - 1;   // clamp loads; stores guarded
  }

  const float* Aph[2];
  Aph[0] = A1;
  Aph[1] = TWO ? A2 : A1;
  const float* Wph[2];
  Wph[0] = W1;
  Wph[1] = TWO ? W2 : W1;

  // prologue: stage chunk 0
  float4 wreg[NSTG];
  #pragma unroll
  for (int i = 0; i < NSTG; ++i)
    wreg[i] = *(const float4*)(Wph[0] + tid * 4 + i * 1024);
  #pragma unroll
  for (int i = 0; i < NSTG; ++i)
    *(float4*)&sW[0][tid * 4 + i * 1024] = wreg[i];
  __syncthreads();

  float acc[4][CPT];
  #pragma unroll
  for (int r = 0; r < 4; ++r)
    #pragma unroll
    for (int c = 0; c < CPT; ++c) acc[r][c] = 0.f;

  for (int cc = 0; cc < NCHUNK; ++cc) {
    // prefetch next weight chunk into registers (in flight during compute)
    if (cc + 1 < NCHUNK) {
      const float* Wn = Wph[(cc + 1) >> 2] + ((cc + 1) & 3) * CF;
      #pragma unroll
      for (int i = 0; i < NSTG; ++i)
        wreg[i] = *(const float4*)(Wn + tid * 4 + i * 1024);
    }

    const float* __restrict__ A = Aph[cc >> 2];
    const int kc = (cc & 3) * 32;
    const float* __restrict__ sWb = sW[cc & 1];

    #pragma unroll
    for (int kk = 0; kk < 32; kk += 4) {
      float4 h4[4];
      #pragma unroll
      for (int r = 0; r < 4; ++r)
        h4[r] = *(const float4*)(A + (size_t)rowc[r] * K_DIM + kc + kk);
      #pragma unroll
      for (int kq = 0; kq < 4; ++kq) {
        float4 w4[NI];
        #pragma unroll
        for (int i = 0; i < NI; ++i)
          w4[i] = *(const float4*)&sWb[(kk + kq) * DOUT + cg * 4 + i * 32];
        #pragma unroll
        for (int r = 0; r < 4; ++r) {
          const float h = ((const float*)&h4[r])[kq];
          #pragma unroll
          for (int i = 0; i < NI; ++i) {
            acc[r][4 * i + 0] = fmaf(h, w4[i].x, acc[r][4 * i + 0]);
            acc[r][4 * i + 1] = fmaf(h, w4[i].y, acc[r][4 * i + 1]);
            acc[r][4 * i + 2] = fmaf(h, w4[i].z, acc[r][4 * i + 2]);
            acc[r][4 * i + 3] = fmaf(h, w4[i].w, acc[r][4 * i + 3]);
          }
        }
      }
    }

    // commit prefetched chunk to the other LDS buffer
    if (cc + 1 < NCHUNK) {
      #pragma unroll
      for (int i = 0; i < NSTG; ++i)
        *(float4*)&sW[(cc + 1) & 1][tid * 4 + i * 1024] = wreg[i];
    }
    __syncthreads();
  }

  // epilogue: bias (+ReLU), coalesced float4 stores
  #pragma unroll
  for (int i = 0; i < NI; ++i) {
    const float4 b4 = *(const float4*)&bias[cg * 4 + i * 32];
    #pragma unroll
    for (int r = 0; r < 4; ++r) {
      const int v = row0 + r;
      if (v < N_NODES) {
        float4 o;
        o.x = acc[r][4 * i + 0] + b4.x;
        o.y = acc[r][4 * i + 1] + b4.y;
        o.z = acc[r][4 * i + 2] + b4.z;
        o.w = acc[r][4 * i + 3] + b4.w;
        if (RELU) {
          o.x = o.x > 0.f ? o.x : 0.f;
          o.y = o.y > 0.f ? o.y : 0.f;
          o.z = o.z > 0.f ? o.z : 0.f;
          o.w = o.w > 0.f ? o.w : 0.f;
        }
        *(float4*)&out[(size_t)v * DOUT + cg * 4 + i * 32] = o;
      }
    }
  }
}

// ---------------------------------------------------------------- launcher

extern "C" void kernel_launch(void* const* d_in, const int* in_sizes, int n_in,
                              void* d_out, int out_size, void* d_ws, size_t ws_size,
                              hipStream_t stream) {
  const float* x        = (const float*)d_in[0];
  const int*   src      = (const int*)d_in[1];
  const int*   dst      = (const int*)d_in[2];
  const float* w_self0  = (const float*)d_in[3];
  const float* b_self0  = (const float*)d_in[4];
  const float* w_neigh0 = (const float*)d_in[5];
  const float* fc_w     = (const float*)d_in[6];
  const float* fc_b     = (const float*)d_in[7];
  const float* fc2_w    = (const float*)d_in[8];
  const float* fc2_b    = (const float*)d_in[9];
  const float* w_self1  = (const float*)d_in[10];
  const float* b_self1  = (const float*)d_in[11];
  const float* w_neigh1 = (const float*)d_in[12];
  const float* w_self2  = (const float*)d_in[13];
  const float* b_self2  = (const float*)d_in[14];
  const float* w_neigh2 = (const float*)d_in[15];

  char* p = (char*)d_ws;
  auto carve = [&](size_t bytes) {
    void* q = (void*)p;
    p += (bytes + 511) & ~(size_t)511;
    return q;
  };
  float* F0      = (float*)carve((size_t)N_NODES * K_DIM * 4);
  float* F1      = (float*)carve((size_t)N_NODES * K_DIM * 4);
  int*   ssrc    = (int*)carve((size_t)N_EDGES * 4);
  int*   row_ptr = (int*)carve((size_t)(N_NODES + 1) * 4);
  int*   cursor  = (int*)carve((size_t)N_NODES * 4);
  int*   deg     = (int*)carve((size_t)N_NODES * 4);
  int*   excl    = (int*)carve((size_t)N_NODES * 4);
  int*   parts   = (int*)carve(512 * 4);
  float* inv_deg = (float*)carve((size_t)N_NODES * 4);

  // ---- CSR build (by dst)
  hipMemsetAsync(deg, 0, (size_t)N_NODES * 4, stream);
  const int EB = (N_EDGES + 255) / 256;
  deg_kernel<<<EB, 256, 0, stream>>>(dst, deg);
  scan1_kernel<<<NPART, 256, 0, stream>>>(deg, excl, parts);
  scan2_kernel<<<1, 512, 0, stream>>>(parts);
  scan3_kernel<<<((N_NODES + 1) + 255) / 256, 256, 0, stream>>>(excl, parts, deg,
                                                                row_ptr, cursor, inv_deg);
  fill_kernel<<<EB, 256, 0, stream>>>(src, dst, cursor, ssrc);

  // ---- network
  const int AB = (N_NODES + 31) / 32;     // agg blocks
  const int GB = (N_NODES + 127) / 128;   // gemm blocks

  // layer 0: agg(x)->F0 ; out = relu(x@Ws0 + F0@Wn0 + b) -> F1
  agg_kernel<<<AB, 256, 0, stream>>>(x, row_ptr, ssrc, inv_deg, F0);
  gemm_kernel<128, true, true><<<GB, 256, 0, stream>>>(x, F0, w_self0, w_neigh0,
                                                       b_self0, F1);
  // NGNN inner fc layers
  gemm_kernel<128, false, true><<<GB, 256, 0, stream>>>(F1, nullptr, fc_w, nullptr,
                                                        fc_b, F0);
  gemm_kernel<128, false, true><<<GB, 256, 0, stream>>>(F0, nullptr, fc2_w, nullptr,
                                                        fc2_b, F1);
  // layer 1: agg(F1)->F0 ; out -> F0 (alias with A2 is safe, see kernel comment)
  agg_kernel<<<AB, 256, 0, stream>>>(F1, row_ptr, ssrc, inv_deg, F0);
  gemm_kernel<128, true, true><<<GB, 256, 0, stream>>>(F1, F0, w_self1, w_neigh1,
                                                       b_self1, F0);
  // layer 2: agg(F0)->F1 ; out -> d_out (DOUT=64, no activation)
  agg_kernel<<<AB, 256, 0, stream>>>(F0, row_ptr, ssrc, inv_deg, F1);
  gemm_kernel<64, true, false><<<GB, 256, 0, stream>>>(F0, F1, w_self2, w_neigh2,
                                                       b_self2, (float*)d_out);
}